// Round 6
// baseline (825.185 us; speedup 1.0000x reference)
//
#include <hip/hip_runtime.h>
#include <math.h>

#define PI_F 3.14159265358979323846f
// DIAGNOSTIC round: per-kernel REP so every kernel surfaces in rocprof top-5
// above the ~80us harness fills. Per-rep time = dur/REP.
#define REP1 16   // K1 ~8us  -> ~128us
#define REP2 16   // K2 ~6us  -> ~96us
#define REP3 4    // K3+fill  -> ~140us (serial model) / ~72us (overlap model)
#define REP4 8    // K4 ~14us -> ~110us

// Structure = Round-5 (K1/K2 baseline, K3 512thr+fill, K4 active-only).

// ---------------- K1: forward z-DFT (baseline) -----------------------------
__global__ __launch_bounds__(256) void k_dft_z(const float* __restrict__ x,
                                               float2* __restrict__ T1) {
    int bid = blockIdx.x;
    int ih = bid & 1, yg = (bid >> 1) & 7, xx = (bid >> 4) & 15, b = bid >> 8;
    __shared__ float  sx[8192];      // [y8][z64][i16] 32KB
    __shared__ float2 twt[1024];     // [z][kz16] 8KB
    #pragma unroll 1
    for (int rep = 0; rep < REP1; ++rep) {
        float4* sx4 = (float4*)sx;
        const float4* src4 = (const float4*)(x + (size_t)((b * 64 + xx) * 64 + yg * 8) * 2048) + ih * 4;
        #pragma unroll
        for (int t = threadIdx.x; t < 2048; t += 256) {
            int i4 = t & 3, z = (t >> 2) & 63, y = t >> 8;
            sx4[(y * 64 + z) * 4 + i4] = src4[(size_t)y * 512 + z * 8 + i4];
        }
        const float cn = -2.0f * PI_F / 64.0f;
        for (int t = threadIdx.x; t < 1024; t += 256) {
            int z = t >> 4, kz = t & 15;
            float s, c; sincosf(cn * (float)((z * kz) & 63), &s, &c);
            twt[t] = make_float2(c, s);
        }
        __syncthreads();
        int ig = threadIdx.x & 3, kz2 = (threadIdx.x >> 2) & 7, y8 = threadIdx.x >> 5;
        float ar0[4], ai0[4], ar1[4], ai1[4];
        #pragma unroll
        for (int j = 0; j < 4; j++) { ar0[j] = ai0[j] = ar1[j] = ai1[j] = 0.f; }
        const float4* twv = (const float4*)twt;
        #pragma unroll 8
        for (int z = 0; z < 64; z++) {
            float4 va = sx4[(y8 * 64 + z) * 4 + ig];
            float4 tp = twv[z * 8 + kz2];
            float v[4] = {va.x, va.y, va.z, va.w};
            #pragma unroll
            for (int j = 0; j < 4; j++) {
                ar0[j] = fmaf(v[j], tp.x, ar0[j]);
                ai0[j] = fmaf(v[j], tp.y, ai0[j]);
                ar1[j] = fmaf(v[j], tp.z, ar1[j]);
                ai1[j] = fmaf(v[j], tp.w, ai1[j]);
            }
        }
        int y = yg * 8 + y8, kz0 = kz2 * 2, i0 = ih * 16 + ig * 4;
        float2* dst = T1 + (size_t)((b * 16 + xx) * 64 + y) * 512;
        float4* d0 = (float4*)(dst + kz0 * 32 + i0);
        d0[0] = make_float4(ar0[0], ai0[0], ar0[1], ai0[1]);
        d0[1] = make_float4(ar0[2], ai0[2], ar0[3], ai0[3]);
        float4* d1 = (float4*)(dst + (kz0 + 1) * 32 + i0);
        d1[0] = make_float4(ar1[0], ai1[0], ar1[1], ai1[1]);
        d1[1] = make_float4(ar1[2], ai1[2], ar1[3], ai1[3]);
        __syncthreads();
        asm volatile("" ::: "memory");
    }
}

// ---------------- K2: forward y-DFT (baseline) -----------------------------
__global__ __launch_bounds__(256) void k_dft_y(const float2* __restrict__ T1,
                                               float2* __restrict__ XH) {
    int bid = blockIdx.x;
    int ih = bid & 1, kzg = (bid >> 1) & 3, xx = (bid >> 3) & 15, b = bid >> 7;
    __shared__ float4 sT4[2304];     // ~37KB
    __shared__ float2 twt[1024];     // 8KB
    #pragma unroll 1
    for (int rep = 0; rep < REP2; ++rep) {
        const float4* Tg4 = (const float4*)T1;
        size_t gbase = (size_t)(b * 16 + xx) * 64 * 256;
        #pragma unroll
        for (int t = threadIdx.x; t < 2048; t += 256) {
            int i4 = t & 7, kz4 = (t >> 3) & 3, y = t >> 5;
            sT4[kz4 * 576 + y * 9 + i4] =
                Tg4[gbase + (size_t)y * 256 + (kzg * 4 + kz4) * 16 + ih * 8 + i4];
        }
        const float cn = -2.0f * PI_F / 64.0f;
        for (int t = threadIdx.x; t < 1024; t += 256) {
            int y = t >> 4, ky = t & 15;
            float s, c; sincosf(cn * (float)((y * ky) & 63), &s, &c);
            twt[t] = make_float2(c, s);
        }
        __syncthreads();
        int ig = threadIdx.x & 7, ky2 = (threadIdx.x >> 3) & 7, kz4 = threadIdx.x >> 6;
        float ar[2][2], ai[2][2];
        #pragma unroll
        for (int h = 0; h < 2; h++) { ar[h][0] = ar[h][1] = ai[h][0] = ai[h][1] = 0.f; }
        const float4* twv = (const float4*)twt;
        #pragma unroll 8
        for (int y = 0; y < 64; y++) {
            float4 a  = sT4[kz4 * 576 + y * 9 + ig];
            float4 tp = twv[y * 8 + ky2];
            float xr[2] = {a.x, a.z}, xi[2] = {a.y, a.w};
            #pragma unroll
            for (int j = 0; j < 2; j++) {
                ar[0][j] += xr[j] * tp.x - xi[j] * tp.y;
                ai[0][j] += xr[j] * tp.y + xi[j] * tp.x;
                ar[1][j] += xr[j] * tp.z - xi[j] * tp.w;
                ai[1][j] += xr[j] * tp.w + xi[j] * tp.z;
            }
        }
        int kz = kzg * 4 + kz4;
        #pragma unroll
        for (int h = 0; h < 2; h++) {
            int ky = ky2 * 2 + h;
            float2* dp = XH + (((size_t)(b * 16 + xx) * 16 + ky) * 16 + kz) * 32 + ih * 16 + ig * 2;
            *(float4*)dp = make_float4(ar[h][0], ai[h][0], ar[h][1], ai[h][1]);
        }
        __syncthreads();
        asm volatile("" ::: "memory");
    }
}

// ---------------- K3: fused mid + zero-fill (R5 structure) -----------------
__global__ __launch_bounds__(512) void k_mid(const float2* __restrict__ XH,
                                             const float* __restrict__ wr,
                                             const float* __restrict__ wi,
                                             float2* __restrict__ G,
                                             float* __restrict__ out) {
    int bid = blockIdx.x;
    if (bid >= 256) {
        int f = bid - 256;
        int b = f / 384, rem = f - b * 384;
        float4* d4 = (float4*)(out + (size_t)(b * 64 + 16) * 131072) + (size_t)rem * 4096;
        #pragma unroll 1
        for (int rep = 0; rep < REP3; ++rep) {
            #pragma unroll
            for (int r = 0; r < 8; ++r)
                d4[r * 512 + threadIdx.x] = make_float4(0.f, 0.f, 0.f, 0.f);
            asm volatile("" ::: "memory");
        }
        return;
    }
    int ky = bid & 15, xx = bid >> 4;
    __shared__ float2 sA[4 * 528];
    __shared__ float2 sB[4 * 576];
    __shared__ float2 twt[1024];
    #pragma unroll 1
    for (int rep = 0; rep < REP3; ++rep) {
        for (int t = threadIdx.x; t < 2048; t += 512) {
            int b = t >> 9, kz = (t >> 5) & 15, i = t & 31;
            sA[b * 528 + kz * 33 + i] =
                XH[(((size_t)(b * 16 + xx) * 16 + ky) * 16 + kz) * 32 + i];
        }
        const float cn32 = -2.0f * PI_F / 32.0f;
        for (int t = threadIdx.x; t < 1024; t += 512) {
            int m = t >> 5, k = t & 31;
            float s, c; sincosf(cn32 * (float)((m * k) & 31), &s, &c);
            twt[t] = make_float2(c, s);
        }
        __syncthreads();
        const float4* twv = (const float4*)twt;
        // phase 1
        {
            int kz = threadIdx.x & 15, kig = (threadIdx.x >> 4) & 7, b = threadIdx.x >> 7;
            float xr[4], xi[4];
            #pragma unroll
            for (int j = 0; j < 4; j++) { xr[j] = xi[j] = 0.f; }
            #pragma unroll 8
            for (int i = 0; i < 32; i++) {
                float2 a   = sA[b * 528 + kz * 33 + i];
                float4 tp0 = twv[i * 16 + kig * 2];
                float4 tp1 = twv[i * 16 + kig * 2 + 1];
                xr[0] += a.x * tp0.x - a.y * tp0.y;  xi[0] += a.x * tp0.y + a.y * tp0.x;
                xr[1] += a.x * tp0.z - a.y * tp0.w;  xi[1] += a.x * tp0.w + a.y * tp0.z;
                xr[2] += a.x * tp1.x - a.y * tp1.y;  xi[2] += a.x * tp1.y + a.y * tp1.x;
                xr[3] += a.x * tp1.z - a.y * tp1.w;  xi[3] += a.x * tp1.w + a.y * tp1.z;
            }
            #pragma unroll
            for (int j = 0; j < 4; j++)
                sB[b * 576 + (kig * 4 + j) * 18 + kz] = make_float2(xr[j], xi[j]);
        }
        __syncthreads();
        // phase 2
        {
            int kzg = threadIdx.x & 3, o = (threadIdx.x >> 2) & 31, b = threadIdx.x >> 7;
            int wbase = xx * 256 + ky * 16 + kzg * 4;
            float Fr[4], Fi[4];
            #pragma unroll
            for (int q = 0; q < 4; q++) { Fr[q] = Fi[q] = 0.f; }
            const float4* sB4 = (const float4*)sB;
            #pragma unroll 4
            for (int ki = 0; ki < 32; ki++) {
                float4 a01 = sB4[b * 288 + ki * 9 + kzg * 2];
                float4 a23 = sB4[b * 288 + ki * 9 + kzg * 2 + 1];
                float4 w4r = *(const float4*)(wr + (size_t)(ki * 32 + o) * 4096 + wbase);
                float4 w4i = *(const float4*)(wi + (size_t)(ki * 32 + o) * 4096 + wbase);
                float xr[4]  = {a01.x, a01.z, a23.x, a23.z};
                float xi[4]  = {a01.y, a01.w, a23.y, a23.w};
                float wrv[4] = {w4r.x, w4r.y, w4r.z, w4r.w};
                float wiv[4] = {w4i.x, w4i.y, w4i.z, w4i.w};
                #pragma unroll
                for (int q = 0; q < 4; q++) {
                    Fr[q] += xr[q] * wrv[q] - xi[q] * wiv[q];
                    Fi[q] += xr[q] * wiv[q] + xi[q] * wrv[q];
                }
            }
            __syncthreads();
            #pragma unroll
            for (int q = 0; q < 4; q++) {
                int kz = kzg * 4 + q;
                sA[b * 528 + kz * 33 + o] = make_float2(Fr[q], Fi[q]);
            }
        }
        __syncthreads();
        // phase 3
        {
            int kz = threadIdx.x & 15, cog = (threadIdx.x >> 4) & 7, b = threadIdx.x >> 7;
            float gr[4], gi[4];
            #pragma unroll
            for (int j = 0; j < 4; j++) { gr[j] = gi[j] = 0.f; }
            #pragma unroll 8
            for (int o = 0; o < 32; o++) {
                float2 f   = sA[b * 528 + kz * 33 + o];
                float4 tp0 = twv[o * 16 + cog * 2];
                float4 tp1 = twv[o * 16 + cog * 2 + 1];
                gr[0] += f.x * tp0.x + f.y * tp0.y;  gi[0] += f.y * tp0.x - f.x * tp0.y;
                gr[1] += f.x * tp0.z + f.y * tp0.w;  gi[1] += f.y * tp0.z - f.x * tp0.w;
                gr[2] += f.x * tp1.x + f.y * tp1.y;  gi[2] += f.y * tp1.x - f.x * tp1.y;
                gr[3] += f.x * tp1.z + f.y * tp1.w;  gi[3] += f.y * tp1.z - f.x * tp1.w;
            }
            float2* dp = G + (((size_t)(b * 16 + xx) * 16 + ky) * 16 + kz) * 32 + cog * 4;
            ((float4*)dp)[0] = make_float4(gr[0], gi[0], gr[1], gi[1]);
            ((float4*)dp)[1] = make_float4(gr[2], gi[2], gr[3], gi[3]);
        }
        __syncthreads();
        asm volatile("" ::: "memory");
    }
}

// ---------------- K4: z-IDFT + y-IDFT + Re + scale (active only) -----------
__global__ __launch_bounds__(256) void k_idft_zy(const float2* __restrict__ G,
                                                 float* __restrict__ out) {
    int bid = blockIdx.x;
    int ch = bid & 1, zc = (bid >> 1) & 7, xx = (bid >> 4) & 15, b = bid >> 8;
    float* dstb = out + (size_t)(b * 64 + xx) * 131072;
    __shared__ float2 sH[128 * 18];
    __shared__ float2 twy[1024];
    __shared__ float2 twz[8 * 17];
    #pragma unroll 1
    for (int rep = 0; rep < REP4; ++rep) {
        const float cp = 2.0f * PI_F / 64.0f;
        for (int t = threadIdx.x; t < 1024; t += 256) {
            int ky = t >> 6, y = t & 63;
            float s, c; sincosf(cp * (float)((ky * y) & 63), &s, &c);
            twy[t] = make_float2(c, s);
        }
        if (threadIdx.x < 128) {
            int dz = threadIdx.x >> 4, kz = threadIdx.x & 15;
            int z = zc * 8 + dz;
            float s, c; sincosf(cp * (float)((kz * z) & 63), &s, &c);
            twz[dz * 17 + kz] = make_float2(c, s);
        }
        __syncthreads();
        // phase Z
        {
            int coq = threadIdx.x & 1, dz = (threadIdx.x >> 1) & 7, ky = threadIdx.x >> 4;
            const float2* Gb = G + ((size_t)(b * 16 + xx) * 16 + ky) * 512 + ch * 16 + coq * 8;
            float Hr[8], Hi[8];
            #pragma unroll
            for (int j = 0; j < 8; j++) { Hr[j] = Hi[j] = 0.f; }
            #pragma unroll 4
            for (int kz = 0; kz < 16; kz++) {
                float2 tz = twz[dz * 17 + kz];
                #pragma unroll
                for (int k = 0; k < 4; k++) {
                    float4 g = *(const float4*)(Gb + kz * 32 + k * 2);
                    Hr[2 * k]     += g.x * tz.x - g.y * tz.y;
                    Hi[2 * k]     += g.x * tz.y + g.y * tz.x;
                    Hr[2 * k + 1] += g.z * tz.x - g.w * tz.y;
                    Hi[2 * k + 1] += g.z * tz.y + g.w * tz.x;
                }
            }
            float2* hp = sH + (ky * 8 + dz) * 18 + coq * 8;
            #pragma unroll
            for (int k = 0; k < 4; k++)
                *(float4*)(hp + k * 2) = make_float4(Hr[2 * k], Hi[2 * k], Hr[2 * k + 1], Hi[2 * k + 1]);
        }
        __syncthreads();
        // phase Y
        {
            int cog = threadIdx.x & 1, dz = (threadIdx.x >> 1) & 7, yg = threadIdx.x >> 4;
            float acc[4][8];
            #pragma unroll
            for (int yl = 0; yl < 4; yl++)
                #pragma unroll
                for (int cl = 0; cl < 8; cl++) acc[yl][cl] = 0.f;
            const float4* twy4 = (const float4*)twy;
            const float4* sH4 = (const float4*)sH;
            for (int ky = 0; ky < 16; ky++) {
                float4 t0 = twy4[ky * 32 + yg * 2 + 0];
                float4 t1 = twy4[ky * 32 + yg * 2 + 1];
                float4 h0 = sH4[(ky * 8 + dz) * 9 + cog * 4 + 0];
                float4 h1 = sH4[(ky * 8 + dz) * 9 + cog * 4 + 1];
                float4 h2 = sH4[(ky * 8 + dz) * 9 + cog * 4 + 2];
                float4 h3 = sH4[(ky * 8 + dz) * 9 + cog * 4 + 3];
                float tc[4] = {t0.x, t0.z, t1.x, t1.z};
                float ts[4] = {t0.y, t0.w, t1.y, t1.w};
                float hr[8] = {h0.x, h0.z, h1.x, h1.z, h2.x, h2.z, h3.x, h3.z};
                float hi[8] = {h0.y, h0.w, h1.y, h1.w, h2.y, h2.w, h3.y, h3.w};
                #pragma unroll
                for (int yl = 0; yl < 4; yl++)
                    #pragma unroll
                    for (int cl = 0; cl < 8; cl++)
                        acc[yl][cl] += tc[yl] * hr[cl] - ts[yl] * hi[cl];
            }
            const float sc = 1.0f / 131072.0f;
            #pragma unroll
            for (int yl = 0; yl < 4; yl++) {
                int y = yg * 4 + yl;
                float4* d4 = (float4*)(dstb + ((size_t)y * 64 + zc * 8 + dz) * 32 + ch * 16 + cog * 8);
                d4[0] = make_float4(acc[yl][0] * sc, acc[yl][1] * sc, acc[yl][2] * sc, acc[yl][3] * sc);
                d4[1] = make_float4(acc[yl][4] * sc, acc[yl][5] * sc, acc[yl][6] * sc, acc[yl][7] * sc);
            }
        }
        __syncthreads();
        asm volatile("" ::: "memory");
    }
}

extern "C" void kernel_launch(void* const* d_in, const int* in_sizes, int n_in,
                              void* d_out, int out_size, void* d_ws, size_t ws_size,
                              hipStream_t stream) {
    const float* x  = (const float*)d_in[0];
    const float* wr = (const float*)d_in[1];
    const float* wi = (const float*)d_in[2];
    float* out = (float*)d_out;
    char*  ws  = (char*)d_ws;
    float2* T1 = (float2*)ws;
    float2* XH = (float2*)(ws + (size_t)16777216);
    float2* Gb = (float2*)(ws + (size_t)16777216 + 4194304);

    k_dft_z  <<<1024, 256, 0, stream>>>(x, T1);
    k_dft_y  <<< 512, 256, 0, stream>>>(T1, XH);
    k_mid    <<<1792, 512, 0, stream>>>(XH, wr, wi, Gb, out);
    k_idft_zy<<<1024, 256, 0, stream>>>(Gb, out);
}

// Round 8
// 312.667 us; speedup vs baseline: 2.6392x; 2.6392x over previous
//
#include <hip/hip_runtime.h>
#include <math.h>

#define PI_F 3.14159265358979323846f

// Shapes: B=4, X=Y=Z=64, CIN=COUT=32, modes 16.
// Round-8 = Round-7 resubmitted (infra failure, never measured):
//  (a) __sinf/__cosf twiddles everywhere (kills sincosf libcall bloat:
//      ~1.1k calls/block), (b) K4 rewritten:
//   phase Z thread=(co16,dz8,kyg2) -> coalesced 128B G loads, twz in regs,
//   sH stride 17 float2 -> conflict-free phase-Y reads (was 8-way writes).
// Measured (R6 REP diag): K1~8us K2~6us K3+fill~36us K4~31us + ~212us floor.

// ---------------- K1: forward z-DFT (baseline + fast trig) -----------------
// grid 1024 = (b4, x16, yg8, ih2); block 256; tile 2kz x 4i per thread.
__global__ __launch_bounds__(256) void k_dft_z(const float* __restrict__ x,
                                               float2* __restrict__ T1) {
    int bid = blockIdx.x;
    int ih = bid & 1, yg = (bid >> 1) & 7, xx = (bid >> 4) & 15, b = bid >> 8;
    __shared__ float  sx[8192];      // [y8][z64][i16] 32KB
    __shared__ float2 twt[1024];     // [z][kz16] 8KB
    float4* sx4 = (float4*)sx;
    const float4* src4 = (const float4*)(x + (size_t)((b * 64 + xx) * 64 + yg * 8) * 2048) + ih * 4;
    #pragma unroll
    for (int t = threadIdx.x; t < 2048; t += 256) {
        int i4 = t & 3, z = (t >> 2) & 63, y = t >> 8;
        sx4[(y * 64 + z) * 4 + i4] = src4[(size_t)y * 512 + z * 8 + i4];
    }
    const float cn = -2.0f * PI_F / 64.0f;
    for (int t = threadIdx.x; t < 1024; t += 256) {
        int z = t >> 4, kz = t & 15;
        float a = cn * (float)((z * kz) & 63);
        twt[t] = make_float2(__cosf(a), __sinf(a));
    }
    __syncthreads();
    int ig = threadIdx.x & 3, kz2 = (threadIdx.x >> 2) & 7, y8 = threadIdx.x >> 5;
    float ar0[4], ai0[4], ar1[4], ai1[4];
    #pragma unroll
    for (int j = 0; j < 4; j++) { ar0[j] = ai0[j] = ar1[j] = ai1[j] = 0.f; }
    const float4* twv = (const float4*)twt;   // [z][8]: (c0,s0,c1,s1) per kz-pair
    #pragma unroll 8
    for (int z = 0; z < 64; z++) {
        float4 va = sx4[(y8 * 64 + z) * 4 + ig];
        float4 tp = twv[z * 8 + kz2];
        float v[4] = {va.x, va.y, va.z, va.w};
        #pragma unroll
        for (int j = 0; j < 4; j++) {
            ar0[j] = fmaf(v[j], tp.x, ar0[j]);
            ai0[j] = fmaf(v[j], tp.y, ai0[j]);
            ar1[j] = fmaf(v[j], tp.z, ar1[j]);
            ai1[j] = fmaf(v[j], tp.w, ai1[j]);
        }
    }
    int y = yg * 8 + y8, kz0 = kz2 * 2, i0 = ih * 16 + ig * 4;
    float2* dst = T1 + (size_t)((b * 16 + xx) * 64 + y) * 512;
    float4* d0 = (float4*)(dst + kz0 * 32 + i0);
    d0[0] = make_float4(ar0[0], ai0[0], ar0[1], ai0[1]);
    d0[1] = make_float4(ar0[2], ai0[2], ar0[3], ai0[3]);
    float4* d1 = (float4*)(dst + (kz0 + 1) * 32 + i0);
    d1[0] = make_float4(ar1[0], ai1[0], ar1[1], ai1[1]);
    d1[1] = make_float4(ar1[2], ai1[2], ar1[3], ai1[3]);
}

// ---------------- K2: forward y-DFT (baseline + fast trig) -----------------
// grid 512 = (b4, x16, kzg4, ih2); block 256; tile 2ky x 2i per thread.
__global__ __launch_bounds__(256) void k_dft_y(const float2* __restrict__ T1,
                                               float2* __restrict__ XH) {
    int bid = blockIdx.x;
    int ih = bid & 1, kzg = (bid >> 1) & 3, xx = (bid >> 3) & 15, b = bid >> 7;
    __shared__ float4 sT4[2304];     // [kz4][y(stride 9)][i4 8] ~37KB
    __shared__ float2 twt[1024];     // [y][ky16] 8KB
    const float4* Tg4 = (const float4*)T1;
    size_t gbase = (size_t)(b * 16 + xx) * 64 * 256;
    #pragma unroll
    for (int t = threadIdx.x; t < 2048; t += 256) {
        int i4 = t & 7, kz4 = (t >> 3) & 3, y = t >> 5;
        sT4[kz4 * 576 + y * 9 + i4] =
            Tg4[gbase + (size_t)y * 256 + (kzg * 4 + kz4) * 16 + ih * 8 + i4];
    }
    const float cn = -2.0f * PI_F / 64.0f;
    for (int t = threadIdx.x; t < 1024; t += 256) {
        int y = t >> 4, ky = t & 15;
        float a = cn * (float)((y * ky) & 63);
        twt[t] = make_float2(__cosf(a), __sinf(a));
    }
    __syncthreads();
    int ig = threadIdx.x & 7, ky2 = (threadIdx.x >> 3) & 7, kz4 = threadIdx.x >> 6;
    float ar[2][2], ai[2][2];
    #pragma unroll
    for (int h = 0; h < 2; h++) { ar[h][0] = ar[h][1] = ai[h][0] = ai[h][1] = 0.f; }
    const float4* twv = (const float4*)twt;
    #pragma unroll 8
    for (int y = 0; y < 64; y++) {
        float4 a  = sT4[kz4 * 576 + y * 9 + ig];   // (xr0,xi0,xr1,xi1)
        float4 tp = twv[y * 8 + ky2];              // (c0,s0,c1,s1)
        float xr[2] = {a.x, a.z}, xi[2] = {a.y, a.w};
        #pragma unroll
        for (int j = 0; j < 2; j++) {
            ar[0][j] += xr[j] * tp.x - xi[j] * tp.y;
            ai[0][j] += xr[j] * tp.y + xi[j] * tp.x;
            ar[1][j] += xr[j] * tp.z - xi[j] * tp.w;
            ai[1][j] += xr[j] * tp.w + xi[j] * tp.z;
        }
    }
    int kz = kzg * 4 + kz4;
    #pragma unroll
    for (int h = 0; h < 2; h++) {
        int ky = ky2 * 2 + h;
        float2* dp = XH + (((size_t)(b * 16 + xx) * 16 + ky) * 16 + kz) * 32 + ih * 16 + ig * 2;
        *(float4*)dp = make_float4(ar[h][0], ai[h][0], ar[h][1], ai[h][1]);
    }
}

// ---------------- K3: fused i-DFT + w-mul + o-IDFT + zero-fill -------------
// grid 1792 = 256 compute (x16, ky16) + 1536 fill; block 512.
__global__ __launch_bounds__(512) void k_mid(const float2* __restrict__ XH,
                                             const float* __restrict__ wr,
                                             const float* __restrict__ wi,
                                             float2* __restrict__ G,
                                             float* __restrict__ out) {
    int bid = blockIdx.x;
    if (bid >= 256) {
        // zero-fill out[b][16..63][*][*][*]: 1536 blocks x 64KB contiguous.
        int f = bid - 256;
        int b = f / 384, rem = f - b * 384;
        float4* d4 = (float4*)(out + (size_t)(b * 64 + 16) * 131072) + (size_t)rem * 4096;
        #pragma unroll
        for (int r = 0; r < 8; ++r)
            d4[r * 512 + threadIdx.x] = make_float4(0.f, 0.f, 0.f, 0.f);
        return;
    }
    int ky = bid & 15, xx = bid >> 4;
    __shared__ float2 sA[4 * 528];   // [b][kz(stride33)][i] ; reused as F[b][kz][o]
    __shared__ float2 sB[4 * 576];   // [b][ki(stride18)][kz]
    __shared__ float2 twt[1024];     // [m][k] = exp(-2pi i mk/32)
    for (int t = threadIdx.x; t < 2048; t += 512) {
        int b = t >> 9, kz = (t >> 5) & 15, i = t & 31;
        sA[b * 528 + kz * 33 + i] =
            XH[(((size_t)(b * 16 + xx) * 16 + ky) * 16 + kz) * 32 + i];
    }
    const float cn32 = -2.0f * PI_F / 32.0f;
    for (int t = threadIdx.x; t < 1024; t += 512) {
        int m = t >> 5, k = t & 31;
        float a = cn32 * (float)((m * k) & 31);
        twt[t] = make_float2(__cosf(a), __sinf(a));
    }
    __syncthreads();
    const float4* twv = (const float4*)twt;
    // phase 1: X2[b][ki][kz] = sum_i tw[ki,i] * XH[b][kz][i]  (4ki x 1kz per thread)
    {
        int kz = threadIdx.x & 15, kig = (threadIdx.x >> 4) & 7, b = threadIdx.x >> 7;
        float xr[4], xi[4];
        #pragma unroll
        for (int j = 0; j < 4; j++) { xr[j] = xi[j] = 0.f; }
        #pragma unroll 8
        for (int i = 0; i < 32; i++) {
            float2 a   = sA[b * 528 + kz * 33 + i];
            float4 tp0 = twv[i * 16 + kig * 2];       // ki = kig*4+0,1
            float4 tp1 = twv[i * 16 + kig * 2 + 1];   // ki = kig*4+2,3
            xr[0] += a.x * tp0.x - a.y * tp0.y;  xi[0] += a.x * tp0.y + a.y * tp0.x;
            xr[1] += a.x * tp0.z - a.y * tp0.w;  xi[1] += a.x * tp0.w + a.y * tp0.z;
            xr[2] += a.x * tp1.x - a.y * tp1.y;  xi[2] += a.x * tp1.y + a.y * tp1.x;
            xr[3] += a.x * tp1.z - a.y * tp1.w;  xi[3] += a.x * tp1.w + a.y * tp1.z;
        }
        #pragma unroll
        for (int j = 0; j < 4; j++)
            sB[b * 576 + (kig * 4 + j) * 18 + kz] = make_float2(xr[j], xi[j]);
    }
    __syncthreads();
    // phase 2: F[b][kz][o] = sum_ki X2[b][ki][kz] * w[ki,o]  (1o x 4kz per thread)
    {
        int kzg = threadIdx.x & 3, o = (threadIdx.x >> 2) & 31, b = threadIdx.x >> 7;
        int wbase = xx * 256 + ky * 16 + kzg * 4;
        float Fr[4], Fi[4];
        #pragma unroll
        for (int q = 0; q < 4; q++) { Fr[q] = Fi[q] = 0.f; }
        const float4* sB4 = (const float4*)sB;     // f4 stride 9 per ki
        #pragma unroll 4
        for (int ki = 0; ki < 32; ki++) {
            float4 a01 = sB4[b * 288 + ki * 9 + kzg * 2];
            float4 a23 = sB4[b * 288 + ki * 9 + kzg * 2 + 1];
            float4 w4r = *(const float4*)(wr + (size_t)(ki * 32 + o) * 4096 + wbase);
            float4 w4i = *(const float4*)(wi + (size_t)(ki * 32 + o) * 4096 + wbase);
            float xr[4]  = {a01.x, a01.z, a23.x, a23.z};
            float xi[4]  = {a01.y, a01.w, a23.y, a23.w};
            float wrv[4] = {w4r.x, w4r.y, w4r.z, w4r.w};
            float wiv[4] = {w4i.x, w4i.y, w4i.z, w4i.w};
            #pragma unroll
            for (int q = 0; q < 4; q++) {
                Fr[q] += xr[q] * wrv[q] - xi[q] * wiv[q];
                Fi[q] += xr[q] * wiv[q] + xi[q] * wrv[q];
            }
        }
        #pragma unroll
        for (int q = 0; q < 4; q++) {
            int kz = kzg * 4 + q;
            sA[b * 528 + kz * 33 + o] = make_float2(Fr[q], Fi[q]);
        }
    }
    __syncthreads();
    // phase 3: G[b][kz][co] = sum_o conj(tw[co,o]) * F[b][kz][o] (4co x 1kz per thread)
    {
        int kz = threadIdx.x & 15, cog = (threadIdx.x >> 4) & 7, b = threadIdx.x >> 7;
        float gr[4], gi[4];
        #pragma unroll
        for (int j = 0; j < 4; j++) { gr[j] = gi[j] = 0.f; }
        #pragma unroll 8
        for (int o = 0; o < 32; o++) {
            float2 f   = sA[b * 528 + kz * 33 + o];
            float4 tp0 = twv[o * 16 + cog * 2];       // co = cog*4+0,1
            float4 tp1 = twv[o * 16 + cog * 2 + 1];   // co = cog*4+2,3
            gr[0] += f.x * tp0.x + f.y * tp0.y;  gi[0] += f.y * tp0.x - f.x * tp0.y;
            gr[1] += f.x * tp0.z + f.y * tp0.w;  gi[1] += f.y * tp0.z - f.x * tp0.w;
            gr[2] += f.x * tp1.x + f.y * tp1.y;  gi[2] += f.y * tp1.x - f.x * tp1.y;
            gr[3] += f.x * tp1.z + f.y * tp1.w;  gi[3] += f.y * tp1.z - f.x * tp1.w;
        }
        float2* dp = G + (((size_t)(b * 16 + xx) * 16 + ky) * 16 + kz) * 32 + cog * 4;
        ((float4*)dp)[0] = make_float4(gr[0], gi[0], gr[1], gi[1]);
        ((float4*)dp)[1] = make_float4(gr[2], gi[2], gr[3], gi[3]);
    }
}

// ---------------- K4 v2: z-IDFT + y-IDFT + Re + scale (active x only) ------
// grid 1024 = (b4, x16, zc8, ch2); block 256.
// Phase Z: thread=(co16,dz8,kyg2): coalesced 128B G loads (in-wave broadcast
// over dz), twz in registers, immediate sH write.
// sH stride 17 float2: phase-Y float2 reads are conflict-free (dz8 x cog2 ->
// 16 distinct bank-pairs; yg lanes broadcast).
__global__ __launch_bounds__(256) void k_idft_zy(const float2* __restrict__ G,
                                                 float* __restrict__ out) {
    int bid = blockIdx.x;
    int ch = bid & 1, zc = (bid >> 1) & 7, xx = (bid >> 4) & 15, b = bid >> 8;
    float* dstb = out + (size_t)(b * 64 + xx) * 131072;   // [y][z][co]
    __shared__ float2 sH[128 * 17];  // row R=ky*8+dz, stride 17, [co16] ~17.4KB
    __shared__ float2 twy[1024];     // [ky][y] 8KB
    __shared__ float2 twz[8 * 17];   // [dz][kz] padded
    const float cp = 2.0f * PI_F / 64.0f;
    for (int t = threadIdx.x; t < 1024; t += 256) {
        int ky = t >> 6, y = t & 63;
        float a = cp * (float)((ky * y) & 63);
        twy[t] = make_float2(__cosf(a), __sinf(a));
    }
    if (threadIdx.x < 128) {
        int dz = threadIdx.x >> 4, kz = threadIdx.x & 15;
        int z = zc * 8 + dz;
        float a = cp * (float)((kz * z) & 63);
        twz[dz * 17 + kz] = make_float2(__cosf(a), __sinf(a));
    }
    __syncthreads();
    // phase Z: H[ky][dz][co] = sum_kz twz[dz,kz] * G[ky][kz][ch*16+co]
    {
        int co = threadIdx.x & 15, dz = (threadIdx.x >> 4) & 7, kyg = threadIdx.x >> 7;
        float tzc[16], tzs[16];
        #pragma unroll
        for (int kz = 0; kz < 16; ++kz) {
            float2 t = twz[dz * 17 + kz];
            tzc[kz] = t.x; tzs[kz] = t.y;
        }
        const float2* Gb0 = G + (size_t)(b * 16 + xx) * 16 * 512 + ch * 16 + co;
        #pragma unroll
        for (int t = 0; t < 8; ++t) {
            int ky = kyg * 8 + t;
            const float2* Gk = Gb0 + (size_t)ky * 512;
            float hr = 0.f, hi = 0.f;
            #pragma unroll
            for (int kz = 0; kz < 16; ++kz) {
                float2 g = Gk[kz * 32];
                hr += g.x * tzc[kz] - g.y * tzs[kz];
                hi += g.x * tzs[kz] + g.y * tzc[kz];
            }
            sH[(ky * 8 + dz) * 17 + co] = make_float2(hr, hi);
        }
    }
    __syncthreads();
    // phase Y: out[y][dz][co16] = Re sum_ky twy[y,ky] * H[ky][dz][co16]
    {
        int cog = threadIdx.x & 1, dz = (threadIdx.x >> 1) & 7, yg = threadIdx.x >> 4;
        float acc[4][8];
        #pragma unroll
        for (int yl = 0; yl < 4; yl++)
            #pragma unroll
            for (int cl = 0; cl < 8; cl++) acc[yl][cl] = 0.f;
        const float4* twy4 = (const float4*)twy;
        for (int ky = 0; ky < 16; ky++) {
            float4 t0 = twy4[ky * 32 + yg * 2 + 0];
            float4 t1 = twy4[ky * 32 + yg * 2 + 1];
            const float2* hp = sH + (ky * 8 + dz) * 17 + cog * 8;
            float hr[8], hi[8];
            #pragma unroll
            for (int cl = 0; cl < 8; ++cl) {
                float2 h = hp[cl];
                hr[cl] = h.x; hi[cl] = h.y;
            }
            float tc[4] = {t0.x, t0.z, t1.x, t1.z};
            float ts[4] = {t0.y, t0.w, t1.y, t1.w};
            #pragma unroll
            for (int yl = 0; yl < 4; yl++)
                #pragma unroll
                for (int cl = 0; cl < 8; cl++)
                    acc[yl][cl] += tc[yl] * hr[cl] - ts[yl] * hi[cl];
        }
        const float sc = 1.0f / 131072.0f;
        #pragma unroll
        for (int yl = 0; yl < 4; yl++) {
            int y = yg * 4 + yl;
            float4* d4 = (float4*)(dstb + ((size_t)y * 64 + zc * 8 + dz) * 32 + ch * 16 + cog * 8);
            d4[0] = make_float4(acc[yl][0] * sc, acc[yl][1] * sc, acc[yl][2] * sc, acc[yl][3] * sc);
            d4[1] = make_float4(acc[yl][4] * sc, acc[yl][5] * sc, acc[yl][6] * sc, acc[yl][7] * sc);
        }
    }
}

extern "C" void kernel_launch(void* const* d_in, const int* in_sizes, int n_in,
                              void* d_out, int out_size, void* d_ws, size_t ws_size,
                              hipStream_t stream) {
    const float* x  = (const float*)d_in[0];
    const float* wr = (const float*)d_in[1];
    const float* wi = (const float*)d_in[2];
    float* out = (float*)d_out;
    char*  ws  = (char*)d_ws;
    // T1: 2,097,152 f2 (16.8 MB); XH: 524,288 f2 (4.2 MB); G: 524,288 f2 (4.2 MB)
    float2* T1 = (float2*)ws;
    float2* XH = (float2*)(ws + (size_t)16777216);
    float2* Gb = (float2*)(ws + (size_t)16777216 + 4194304);

    k_dft_z  <<<1024, 256, 0, stream>>>(x, T1);
    k_dft_y  <<< 512, 256, 0, stream>>>(T1, XH);
    k_mid    <<<1792, 512, 0, stream>>>(XH, wr, wi, Gb, out);  // compute + fill
    k_idft_zy<<<1024, 256, 0, stream>>>(Gb, out);
}

// Round 9
// 286.713 us; speedup vs baseline: 2.8781x; 1.0905x over previous
//
#include <hip/hip_runtime.h>
#include <math.h>

#define PI_F 3.14159265358979323846f

// Shapes: B=4, X=Y=Z=64, CIN=COUT=32, modes 16.
// Round-9 = R5 structure (K1/K2 baseline, K3 512thr+fill) + fast trig +
// K4 v3: stage the 32KB G-slice into LDS ONCE (coalesced), phase Z from LDS
// (kills ~512MB of redundant L2 read traffic measured-inferred from R6),
// sH aliased over the sG LDS region (union, 40.6KB), phase Y = R5 verbatim.

// ---------------- K1: forward z-DFT ----------------------------------------
// grid 1024 = (b4, x16, yg8, ih2); block 256; tile 2kz x 4i per thread.
__global__ __launch_bounds__(256) void k_dft_z(const float* __restrict__ x,
                                               float2* __restrict__ T1) {
    int bid = blockIdx.x;
    int ih = bid & 1, yg = (bid >> 1) & 7, xx = (bid >> 4) & 15, b = bid >> 8;
    __shared__ float  sx[8192];      // [y8][z64][i16] 32KB
    __shared__ float2 twt[1024];     // [z][kz16] 8KB
    float4* sx4 = (float4*)sx;
    const float4* src4 = (const float4*)(x + (size_t)((b * 64 + xx) * 64 + yg * 8) * 2048) + ih * 4;
    #pragma unroll
    for (int t = threadIdx.x; t < 2048; t += 256) {
        int i4 = t & 3, z = (t >> 2) & 63, y = t >> 8;
        sx4[(y * 64 + z) * 4 + i4] = src4[(size_t)y * 512 + z * 8 + i4];
    }
    const float cn = -2.0f * PI_F / 64.0f;
    for (int t = threadIdx.x; t < 1024; t += 256) {
        int z = t >> 4, kz = t & 15;
        float a = cn * (float)((z * kz) & 63);
        twt[t] = make_float2(__cosf(a), __sinf(a));
    }
    __syncthreads();
    int ig = threadIdx.x & 3, kz2 = (threadIdx.x >> 2) & 7, y8 = threadIdx.x >> 5;
    float ar0[4], ai0[4], ar1[4], ai1[4];
    #pragma unroll
    for (int j = 0; j < 4; j++) { ar0[j] = ai0[j] = ar1[j] = ai1[j] = 0.f; }
    const float4* twv = (const float4*)twt;   // [z][8]: (c0,s0,c1,s1) per kz-pair
    #pragma unroll 8
    for (int z = 0; z < 64; z++) {
        float4 va = sx4[(y8 * 64 + z) * 4 + ig];
        float4 tp = twv[z * 8 + kz2];
        float v[4] = {va.x, va.y, va.z, va.w};
        #pragma unroll
        for (int j = 0; j < 4; j++) {
            ar0[j] = fmaf(v[j], tp.x, ar0[j]);
            ai0[j] = fmaf(v[j], tp.y, ai0[j]);
            ar1[j] = fmaf(v[j], tp.z, ar1[j]);
            ai1[j] = fmaf(v[j], tp.w, ai1[j]);
        }
    }
    int y = yg * 8 + y8, kz0 = kz2 * 2, i0 = ih * 16 + ig * 4;
    float2* dst = T1 + (size_t)((b * 16 + xx) * 64 + y) * 512;
    float4* d0 = (float4*)(dst + kz0 * 32 + i0);
    d0[0] = make_float4(ar0[0], ai0[0], ar0[1], ai0[1]);
    d0[1] = make_float4(ar0[2], ai0[2], ar0[3], ai0[3]);
    float4* d1 = (float4*)(dst + (kz0 + 1) * 32 + i0);
    d1[0] = make_float4(ar1[0], ai1[0], ar1[1], ai1[1]);
    d1[1] = make_float4(ar1[2], ai1[2], ar1[3], ai1[3]);
}

// ---------------- K2: forward y-DFT (baseline) -----------------------------
// grid 512 = (b4, x16, kzg4, ih2); block 256; tile 2ky x 2i per thread.
__global__ __launch_bounds__(256) void k_dft_y(const float2* __restrict__ T1,
                                               float2* __restrict__ XH) {
    int bid = blockIdx.x;
    int ih = bid & 1, kzg = (bid >> 1) & 3, xx = (bid >> 3) & 15, b = bid >> 7;
    __shared__ float4 sT4[2304];     // [kz4][y(stride 9)][i4 8] ~37KB
    __shared__ float2 twt[1024];     // [y][ky16] 8KB
    const float4* Tg4 = (const float4*)T1;
    size_t gbase = (size_t)(b * 16 + xx) * 64 * 256;
    #pragma unroll
    for (int t = threadIdx.x; t < 2048; t += 256) {
        int i4 = t & 7, kz4 = (t >> 3) & 3, y = t >> 5;
        sT4[kz4 * 576 + y * 9 + i4] =
            Tg4[gbase + (size_t)y * 256 + (kzg * 4 + kz4) * 16 + ih * 8 + i4];
    }
    const float cn = -2.0f * PI_F / 64.0f;
    for (int t = threadIdx.x; t < 1024; t += 256) {
        int y = t >> 4, ky = t & 15;
        float a = cn * (float)((y * ky) & 63);
        twt[t] = make_float2(__cosf(a), __sinf(a));
    }
    __syncthreads();
    int ig = threadIdx.x & 7, ky2 = (threadIdx.x >> 3) & 7, kz4 = threadIdx.x >> 6;
    float ar[2][2], ai[2][2];
    #pragma unroll
    for (int h = 0; h < 2; h++) { ar[h][0] = ar[h][1] = ai[h][0] = ai[h][1] = 0.f; }
    const float4* twv = (const float4*)twt;
    #pragma unroll 8
    for (int y = 0; y < 64; y++) {
        float4 a  = sT4[kz4 * 576 + y * 9 + ig];   // (xr0,xi0,xr1,xi1)
        float4 tp = twv[y * 8 + ky2];              // (c0,s0,c1,s1)
        float xr[2] = {a.x, a.z}, xi[2] = {a.y, a.w};
        #pragma unroll
        for (int j = 0; j < 2; j++) {
            ar[0][j] += xr[j] * tp.x - xi[j] * tp.y;
            ai[0][j] += xr[j] * tp.y + xi[j] * tp.x;
            ar[1][j] += xr[j] * tp.z - xi[j] * tp.w;
            ai[1][j] += xr[j] * tp.w + xi[j] * tp.z;
        }
    }
    int kz = kzg * 4 + kz4;
    #pragma unroll
    for (int h = 0; h < 2; h++) {
        int ky = ky2 * 2 + h;
        float2* dp = XH + (((size_t)(b * 16 + xx) * 16 + ky) * 16 + kz) * 32 + ih * 16 + ig * 2;
        *(float4*)dp = make_float4(ar[h][0], ai[h][0], ar[h][1], ai[h][1]);
    }
}

// ---------------- K3: fused i-DFT + w-mul + o-IDFT + zero-fill -------------
// grid 1792 = 256 compute (x16, ky16) + 1536 fill; block 512.
__global__ __launch_bounds__(512) void k_mid(const float2* __restrict__ XH,
                                             const float* __restrict__ wr,
                                             const float* __restrict__ wi,
                                             float2* __restrict__ G,
                                             float* __restrict__ out) {
    int bid = blockIdx.x;
    if (bid >= 256) {
        // zero-fill out[b][16..63][*][*][*]: 1536 blocks x 64KB contiguous.
        int f = bid - 256;
        int b = f / 384, rem = f - b * 384;
        float4* d4 = (float4*)(out + (size_t)(b * 64 + 16) * 131072) + (size_t)rem * 4096;
        #pragma unroll
        for (int r = 0; r < 8; ++r)
            d4[r * 512 + threadIdx.x] = make_float4(0.f, 0.f, 0.f, 0.f);
        return;
    }
    int ky = bid & 15, xx = bid >> 4;
    __shared__ float2 sA[4 * 528];   // [b][kz(stride33)][i] ; reused as F[b][kz][o]
    __shared__ float2 sB[4 * 576];   // [b][ki(stride18)][kz]
    __shared__ float2 twt[1024];     // [m][k] = exp(-2pi i mk/32)
    for (int t = threadIdx.x; t < 2048; t += 512) {
        int b = t >> 9, kz = (t >> 5) & 15, i = t & 31;
        sA[b * 528 + kz * 33 + i] =
            XH[(((size_t)(b * 16 + xx) * 16 + ky) * 16 + kz) * 32 + i];
    }
    const float cn32 = -2.0f * PI_F / 32.0f;
    for (int t = threadIdx.x; t < 1024; t += 512) {
        int m = t >> 5, k = t & 31;
        float a = cn32 * (float)((m * k) & 31);
        twt[t] = make_float2(__cosf(a), __sinf(a));
    }
    __syncthreads();
    const float4* twv = (const float4*)twt;
    // phase 1: X2[b][ki][kz] = sum_i tw[ki,i] * XH[b][kz][i]  (4ki x 1kz per thread)
    {
        int kz = threadIdx.x & 15, kig = (threadIdx.x >> 4) & 7, b = threadIdx.x >> 7;
        float xr[4], xi[4];
        #pragma unroll
        for (int j = 0; j < 4; j++) { xr[j] = xi[j] = 0.f; }
        #pragma unroll 8
        for (int i = 0; i < 32; i++) {
            float2 a   = sA[b * 528 + kz * 33 + i];
            float4 tp0 = twv[i * 16 + kig * 2];       // ki = kig*4+0,1
            float4 tp1 = twv[i * 16 + kig * 2 + 1];   // ki = kig*4+2,3
            xr[0] += a.x * tp0.x - a.y * tp0.y;  xi[0] += a.x * tp0.y + a.y * tp0.x;
            xr[1] += a.x * tp0.z - a.y * tp0.w;  xi[1] += a.x * tp0.w + a.y * tp0.z;
            xr[2] += a.x * tp1.x - a.y * tp1.y;  xi[2] += a.x * tp1.y + a.y * tp1.x;
            xr[3] += a.x * tp1.z - a.y * tp1.w;  xi[3] += a.x * tp1.w + a.y * tp1.z;
        }
        #pragma unroll
        for (int j = 0; j < 4; j++)
            sB[b * 576 + (kig * 4 + j) * 18 + kz] = make_float2(xr[j], xi[j]);
    }
    __syncthreads();
    // phase 2: F[b][kz][o] = sum_ki X2[b][ki][kz] * w[ki,o]  (1o x 4kz per thread)
    {
        int kzg = threadIdx.x & 3, o = (threadIdx.x >> 2) & 31, b = threadIdx.x >> 7;
        int wbase = xx * 256 + ky * 16 + kzg * 4;
        float Fr[4], Fi[4];
        #pragma unroll
        for (int q = 0; q < 4; q++) { Fr[q] = Fi[q] = 0.f; }
        const float4* sB4 = (const float4*)sB;     // f4 stride 9 per ki
        #pragma unroll 4
        for (int ki = 0; ki < 32; ki++) {
            float4 a01 = sB4[b * 288 + ki * 9 + kzg * 2];
            float4 a23 = sB4[b * 288 + ki * 9 + kzg * 2 + 1];
            float4 w4r = *(const float4*)(wr + (size_t)(ki * 32 + o) * 4096 + wbase);
            float4 w4i = *(const float4*)(wi + (size_t)(ki * 32 + o) * 4096 + wbase);
            float xr[4]  = {a01.x, a01.z, a23.x, a23.z};
            float xi[4]  = {a01.y, a01.w, a23.y, a23.w};
            float wrv[4] = {w4r.x, w4r.y, w4r.z, w4r.w};
            float wiv[4] = {w4i.x, w4i.y, w4i.z, w4i.w};
            #pragma unroll
            for (int q = 0; q < 4; q++) {
                Fr[q] += xr[q] * wrv[q] - xi[q] * wiv[q];
                Fi[q] += xr[q] * wiv[q] + xi[q] * wrv[q];
            }
        }
        #pragma unroll
        for (int q = 0; q < 4; q++) {
            int kz = kzg * 4 + q;
            sA[b * 528 + kz * 33 + o] = make_float2(Fr[q], Fi[q]);
        }
    }
    __syncthreads();
    // phase 3: G[b][kz][co] = sum_o conj(tw[co,o]) * F[b][kz][o] (4co x 1kz per thread)
    {
        int kz = threadIdx.x & 15, cog = (threadIdx.x >> 4) & 7, b = threadIdx.x >> 7;
        float gr[4], gi[4];
        #pragma unroll
        for (int j = 0; j < 4; j++) { gr[j] = gi[j] = 0.f; }
        #pragma unroll 8
        for (int o = 0; o < 32; o++) {
            float2 f   = sA[b * 528 + kz * 33 + o];
            float4 tp0 = twv[o * 16 + cog * 2];       // co = cog*4+0,1
            float4 tp1 = twv[o * 16 + cog * 2 + 1];   // co = cog*4+2,3
            gr[0] += f.x * tp0.x + f.y * tp0.y;  gi[0] += f.y * tp0.x - f.x * tp0.y;
            gr[1] += f.x * tp0.z + f.y * tp0.w;  gi[1] += f.y * tp0.z - f.x * tp0.w;
            gr[2] += f.x * tp1.x + f.y * tp1.y;  gi[2] += f.y * tp1.x - f.x * tp1.y;
            gr[3] += f.x * tp1.z + f.y * tp1.w;  gi[3] += f.y * tp1.z - f.x * tp1.w;
        }
        float2* dp = G + (((size_t)(b * 16 + xx) * 16 + ky) * 16 + kz) * 32 + cog * 4;
        ((float4*)dp)[0] = make_float4(gr[0], gi[0], gr[1], gi[1]);
        ((float4*)dp)[1] = make_float4(gr[2], gi[2], gr[3], gi[3]);
    }
}

// ---------------- K4 v3: z-IDFT + y-IDFT + Re + scale (active x only) ------
// grid 1024 = (b4, x16, zc8, ch2); block 256.
// Stage the block's 32KB G-slice into LDS ONCE (8 coalesced float4/thread),
// phase Z entirely from LDS (co lanes cover all 32 banks; dz lanes broadcast),
// H held in regs across a barrier, then sH (stride 18) aliased over sG.
// Phase Y identical to the measured R5 kernel.
__global__ __launch_bounds__(256) void k_idft_zy(const float2* __restrict__ G,
                                                 float* __restrict__ out) {
    int bid = blockIdx.x;
    int ch = bid & 1, zc = (bid >> 1) & 7, xx = (bid >> 4) & 15, b = bid >> 8;
    float* dstb = out + (size_t)(b * 64 + xx) * 131072;   // [y][z][co]
    __shared__ float2 sGH[4096];     // phase1: sG[row=ky*16+kz][co16] 32KB;
                                     // phase2 alias: sH[row=ky*8+dz][stride18]
    __shared__ float2 twy[1024];     // [ky][y] 8KB
    __shared__ float2 twz[8 * 17];   // [dz][kz] padded
    const float cp = 2.0f * PI_F / 64.0f;
    for (int t = threadIdx.x; t < 1024; t += 256) {
        int ky = t >> 6, y = t & 63;
        float a = cp * (float)((ky * y) & 63);
        twy[t] = make_float2(__cosf(a), __sinf(a));
    }
    if (threadIdx.x < 128) {
        int dz = threadIdx.x >> 4, kz = threadIdx.x & 15;
        int z = zc * 8 + dz;
        float a = cp * (float)((kz * z) & 63);
        twz[dz * 17 + kz] = make_float2(__cosf(a), __sinf(a));
    }
    // stage G slice (this block's ch-half): 2048 float4, fully coalesced
    {
        const float2* Gb = G + (size_t)(b * 16 + xx) * 8192 + ch * 16;
        for (int t = threadIdx.x; t < 2048; t += 256) {
            int row = t >> 3, idx = t & 7;       // row = ky*16+kz
            int ky = row >> 4, kz = row & 15;
            float4 v = *(const float4*)(Gb + (size_t)ky * 512 + kz * 32 + idx * 2);
            *(float4*)(&sGH[row * 16 + idx * 2]) = v;
        }
    }
    __syncthreads();
    // phase Z from LDS: H[ky][dz][co] = sum_kz twz[dz,kz] * sG[ky*16+kz][co]
    int co = threadIdx.x & 15, dzp = (threadIdx.x >> 4) & 7, kyg = threadIdx.x >> 7;
    float hr[8], hi[8];
    {
        float tzc[16], tzs[16];
        #pragma unroll
        for (int kz = 0; kz < 16; ++kz) {
            float2 t = twz[dzp * 17 + kz];
            tzc[kz] = t.x; tzs[kz] = t.y;
        }
        #pragma unroll
        for (int t = 0; t < 8; ++t) {
            int ky = kyg * 8 + t;
            float r = 0.f, im = 0.f;
            #pragma unroll
            for (int kz = 0; kz < 16; ++kz) {
                float2 g = sGH[(ky * 16 + kz) * 16 + co];
                r  += g.x * tzc[kz] - g.y * tzs[kz];
                im += g.x * tzs[kz] + g.y * tzc[kz];
            }
            hr[t] = r; hi[t] = im;
        }
    }
    __syncthreads();                 // all sG reads complete
    #pragma unroll
    for (int t = 0; t < 8; ++t) {    // write sH over the same LDS (stride 18)
        int ky = kyg * 8 + t;
        sGH[(ky * 8 + dzp) * 18 + co] = make_float2(hr[t], hi[t]);
    }
    __syncthreads();
    // phase Y: out[y][dz][co16] = Re sum_ky twy[y,ky] * H[ky][dz][co16]
    {
        int cog = threadIdx.x & 1, dz = (threadIdx.x >> 1) & 7, yg = threadIdx.x >> 4;
        float acc[4][8];
        #pragma unroll
        for (int yl = 0; yl < 4; yl++)
            #pragma unroll
            for (int cl = 0; cl < 8; cl++) acc[yl][cl] = 0.f;
        const float4* twy4 = (const float4*)twy;
        const float4* sH4 = (const float4*)sGH;   // f4 stride 9 per row
        for (int ky = 0; ky < 16; ky++) {
            float4 t0 = twy4[ky * 32 + yg * 2 + 0];
            float4 t1 = twy4[ky * 32 + yg * 2 + 1];
            float4 h0 = sH4[(ky * 8 + dz) * 9 + cog * 4 + 0];
            float4 h1 = sH4[(ky * 8 + dz) * 9 + cog * 4 + 1];
            float4 h2 = sH4[(ky * 8 + dz) * 9 + cog * 4 + 2];
            float4 h3 = sH4[(ky * 8 + dz) * 9 + cog * 4 + 3];
            float tc[4] = {t0.x, t0.z, t1.x, t1.z};
            float ts[4] = {t0.y, t0.w, t1.y, t1.w};
            float hrv[8] = {h0.x, h0.z, h1.x, h1.z, h2.x, h2.z, h3.x, h3.z};
            float hiv[8] = {h0.y, h0.w, h1.y, h1.w, h2.y, h2.w, h3.y, h3.w};
            #pragma unroll
            for (int yl = 0; yl < 4; yl++)
                #pragma unroll
                for (int cl = 0; cl < 8; cl++)
                    acc[yl][cl] += tc[yl] * hrv[cl] - ts[yl] * hiv[cl];
        }
        const float sc = 1.0f / 131072.0f;
        #pragma unroll
        for (int yl = 0; yl < 4; yl++) {
            int y = yg * 4 + yl;
            float4* d4 = (float4*)(dstb + ((size_t)y * 64 + zc * 8 + dz) * 32 + ch * 16 + cog * 8);
            d4[0] = make_float4(acc[yl][0] * sc, acc[yl][1] * sc, acc[yl][2] * sc, acc[yl][3] * sc);
            d4[1] = make_float4(acc[yl][4] * sc, acc[yl][5] * sc, acc[yl][6] * sc, acc[yl][7] * sc);
        }
    }
}

extern "C" void kernel_launch(void* const* d_in, const int* in_sizes, int n_in,
                              void* d_out, int out_size, void* d_ws, size_t ws_size,
                              hipStream_t stream) {
    const float* x  = (const float*)d_in[0];
    const float* wr = (const float*)d_in[1];
    const float* wi = (const float*)d_in[2];
    float* out = (float*)d_out;
    char*  ws  = (char*)d_ws;
    // T1: 2,097,152 f2 (16.8 MB); XH: 524,288 f2 (4.2 MB); G: 524,288 f2 (4.2 MB)
    float2* T1 = (float2*)ws;
    float2* XH = (float2*)(ws + (size_t)16777216);
    float2* Gb = (float2*)(ws + (size_t)16777216 + 4194304);

    k_dft_z  <<<1024, 256, 0, stream>>>(x, T1);
    k_dft_y  <<< 512, 256, 0, stream>>>(T1, XH);
    k_mid    <<<1792, 512, 0, stream>>>(XH, wr, wi, Gb, out);  // compute + fill
    k_idft_zy<<<1024, 256, 0, stream>>>(Gb, out);
}